// Round 1
// baseline (445.484 us; speedup 1.0000x reference)
//
#include <hip/hip_runtime.h>
#include <hip/hip_bf16.h>

#define NTOK 2048
#define HDIM 1024
#define DDIM 1024
#define NEXP 8

#define BM 64
#define BN 64
#define BK 64
#define LDA 72
#define LDB 72

typedef __bf16 bf16x8 __attribute__((ext_vector_type(8)));
typedef __bf16 bf16x4 __attribute__((ext_vector_type(4)));
typedef float f32x4 __attribute__((ext_vector_type(4)));

__device__ __forceinline__ f32x4 mfma_bf16(bf16x8 a, bf16x8 b, f32x4 c) {
  return __builtin_amdgcn_mfma_f32_16x16x32_bf16(a, b, c, 0, 0, 0);
}

// ---------------- router: logits -> top2 -> lists; also x -> bf16 ----------------
__global__ __launch_bounds__(64) void router_kernel(
    const float* __restrict__ x, const float* __restrict__ rw,
    __bf16* __restrict__ xb, int* __restrict__ counts,
    int* __restrict__ tok_list, float* __restrict__ wt_list)
{
  int n = blockIdx.x;
  int t = threadIdx.x;
  const float* xr = x + (size_t)n * HDIM;
  float acc[NEXP];
#pragma unroll
  for (int e = 0; e < NEXP; ++e) acc[e] = 0.f;
  float xv[16];
#pragma unroll
  for (int i = 0; i < 16; ++i) {
    int h = t + 64 * i;
    float v = xr[h];
    xv[i] = v;
#pragma unroll
    for (int e = 0; e < NEXP; ++e) acc[e] += v * rw[e * HDIM + h];
  }
#pragma unroll
  for (int e = 0; e < NEXP; ++e) {
    float v = acc[e];
#pragma unroll
    for (int off = 32; off > 0; off >>= 1) v += __shfl_xor(v, off, 64);
    acc[e] = v;
  }
#pragma unroll
  for (int i = 0; i < 16; ++i)
    xb[(size_t)n * HDIM + t + 64 * i] = (__bf16)xv[i];

  if (t == 0) {
    int i1 = 0; float l1 = acc[0];
#pragma unroll
    for (int e = 1; e < NEXP; ++e) if (acc[e] > l1) { l1 = acc[e]; i1 = e; }
    int i2 = -1; float l2 = -3.4e38f;
#pragma unroll
    for (int e = 0; e < NEXP; ++e) if (e != i1 && acc[e] > l2) { l2 = acc[e]; i2 = e; }
    // top-2 renormalized softmax: full-softmax denominator cancels
    float m = fmaxf(l1, l2);
    float p1 = __expf(l1 - m), p2 = __expf(l2 - m);
    float inv = 1.f / (p1 + p2);
    int pos1 = atomicAdd(&counts[i1], 1);
    tok_list[i1 * NTOK + pos1] = n * 2;       // hidden row id = 2n + slot
    wt_list[i1 * NTOK + pos1] = p1 * inv;
    int pos2 = atomicAdd(&counts[i2], 1);
    tok_list[i2 * NTOK + pos2] = n * 2 + 1;
    wt_list[i2 * NTOK + pos2] = p2 * inv;
  }
}

// ---------------- up-proj + SwiGLU: hidden[2n+k][d] = silu(g)*u ----------------
__global__ __launch_bounds__(256) void up_kernel(
    const __bf16* __restrict__ xb, const float* __restrict__ up,
    const int* __restrict__ counts, const int* __restrict__ tok_list,
    __bf16* __restrict__ hidden)
{
  int e = blockIdx.z;
  int nrows = counts[e];
  int m0 = blockIdx.x * BM;
  if (m0 >= nrows) return;
  int d0 = blockIdx.y * BN;

  __shared__ __bf16 As[BM][LDA];
  __shared__ __bf16 B1s[BN][LDB];
  __shared__ __bf16 B2s[BN][LDB];
  __shared__ int rows_s[BM];

  int t = threadIdx.x;
  if (t < BM) {
    int idx = m0 + t;
    rows_s[t] = (idx < nrows) ? tok_list[e * NTOK + idx] : -1;
  }
  __syncthreads();

  const float* W = up + (size_t)e * HDIM * (2 * DDIM);

  f32x4 acc1[2][2], acc2[2][2];
#pragma unroll
  for (int i = 0; i < 2; ++i)
#pragma unroll
    for (int j = 0; j < 2; ++j) {
      acc1[i][j] = (f32x4){0.f, 0.f, 0.f, 0.f};
      acc2[i][j] = (f32x4){0.f, 0.f, 0.f, 0.f};
    }

  int wave = t >> 6, lane = t & 63;
  int wm = (wave & 1) * 32, wn = (wave >> 1) * 32;
  int lm = lane & 15, quad = lane >> 4;

  // A staging: 4 threads per row, 16 elems (32B) each
  int arow = t >> 2;
  int ac0 = (t & 3) * 16;
  int rA = rows_s[arow];
  const __bf16* asrc = xb + (size_t)((rA < 0) ? 0 : (rA >> 1)) * HDIM;

  // B staging: 4x4 micro-tile transpose per thread
  int bd = (t & 15) * 4;
  int bk = (t >> 4) * 4;

  for (int k0 = 0; k0 < HDIM; k0 += BK) {
    uint4 av0 = *(const uint4*)(asrc + k0 + ac0);
    uint4 av1 = *(const uint4*)(asrc + k0 + ac0 + 8);
    *(uint4*)&As[arow][ac0] = av0;
    *(uint4*)&As[arow][ac0 + 8] = av1;
#pragma unroll
    for (int h = 0; h < 2; ++h) {
      const float* src = W + (size_t)(k0 + bk) * (2 * DDIM) + h * DDIM + d0 + bd;
      f32x4 r0 = *(const f32x4*)(src);
      f32x4 r1 = *(const f32x4*)(src + 2 * DDIM);
      f32x4 r2 = *(const f32x4*)(src + 4 * DDIM);
      f32x4 r3 = *(const f32x4*)(src + 6 * DDIM);
      __bf16 (*Bs)[LDB] = h ? B2s : B1s;
#pragma unroll
      for (int dd = 0; dd < 4; ++dd) {
        bf16x4 p;
        p[0] = (__bf16)r0[dd];
        p[1] = (__bf16)r1[dd];
        p[2] = (__bf16)r2[dd];
        p[3] = (__bf16)r3[dd];
        *(bf16x4*)&Bs[bd + dd][bk] = p;
      }
    }
    __syncthreads();
#pragma unroll
    for (int kk = 0; kk < BK; kk += 32) {
      int ko = kk + quad * 8;
      bf16x8 a0  = *(const bf16x8*)&As[wm + lm][ko];
      bf16x8 a1  = *(const bf16x8*)&As[wm + 16 + lm][ko];
      bf16x8 b10 = *(const bf16x8*)&B1s[wn + lm][ko];
      bf16x8 b11 = *(const bf16x8*)&B1s[wn + 16 + lm][ko];
      bf16x8 b20 = *(const bf16x8*)&B2s[wn + lm][ko];
      bf16x8 b21 = *(const bf16x8*)&B2s[wn + 16 + lm][ko];
      acc1[0][0] = mfma_bf16(a0, b10, acc1[0][0]);
      acc1[0][1] = mfma_bf16(a0, b11, acc1[0][1]);
      acc1[1][0] = mfma_bf16(a1, b10, acc1[1][0]);
      acc1[1][1] = mfma_bf16(a1, b11, acc1[1][1]);
      acc2[0][0] = mfma_bf16(a0, b20, acc2[0][0]);
      acc2[0][1] = mfma_bf16(a0, b21, acc2[0][1]);
      acc2[1][0] = mfma_bf16(a1, b20, acc2[1][0]);
      acc2[1][1] = mfma_bf16(a1, b21, acc2[1][1]);
    }
    __syncthreads();
  }

#pragma unroll
  for (int i = 0; i < 2; ++i)
#pragma unroll
    for (int j = 0; j < 2; ++j)
#pragma unroll
      for (int r = 0; r < 4; ++r) {
        int lr = wm + i * 16 + quad * 4 + r;   // C/D: row = quad*4 + reg
        int rid = rows_s[lr];
        if (rid >= 0) {
          int gc = d0 + wn + j * 16 + lm;      // C/D: col = lane&15
          float g = acc1[i][j][r], u = acc2[i][j][r];
          float hv = g / (1.f + __expf(-g)) * u;
          hidden[(size_t)rid * DDIM + gc] = (__bf16)hv;
        }
      }
}

// ---------------- down-proj + gate-weighted scatter-add ----------------
__global__ __launch_bounds__(256) void down_kernel(
    const __bf16* __restrict__ hidden, const float* __restrict__ dw,
    const int* __restrict__ counts, const int* __restrict__ tok_list,
    const float* __restrict__ wt_list, float* __restrict__ out)
{
  int e = blockIdx.z;
  int nrows = counts[e];
  int m0 = blockIdx.x * BM;
  if (m0 >= nrows) return;
  int c0 = blockIdx.y * BN;

  __shared__ __bf16 As[BM][LDA];
  __shared__ __bf16 Bs[BN][LDB];
  __shared__ int rows_s[BM];
  __shared__ float wts_s[BM];

  int t = threadIdx.x;
  if (t < BM) {
    int idx = m0 + t;
    rows_s[t] = (idx < nrows) ? tok_list[e * NTOK + idx] : -1;
    wts_s[t] = (idx < nrows) ? wt_list[e * NTOK + idx] : 0.f;
  }
  __syncthreads();

  const float* W = dw + (size_t)e * DDIM * HDIM;

  f32x4 acc[2][2];
#pragma unroll
  for (int i = 0; i < 2; ++i)
#pragma unroll
    for (int j = 0; j < 2; ++j) acc[i][j] = (f32x4){0.f, 0.f, 0.f, 0.f};

  int wave = t >> 6, lane = t & 63;
  int wm = (wave & 1) * 32, wn = (wave >> 1) * 32;
  int lm = lane & 15, quad = lane >> 4;

  int arow = t >> 2;
  int ac0 = (t & 3) * 16;
  int rA = rows_s[arow];
  const __bf16* asrc = hidden + (size_t)((rA < 0) ? 0 : rA) * DDIM;

  int bd = (t & 15) * 4;
  int bk = (t >> 4) * 4;

  for (int k0 = 0; k0 < DDIM; k0 += BK) {
    uint4 av0 = *(const uint4*)(asrc + k0 + ac0);
    uint4 av1 = *(const uint4*)(asrc + k0 + ac0 + 8);
    *(uint4*)&As[arow][ac0] = av0;
    *(uint4*)&As[arow][ac0 + 8] = av1;
    {
      const float* src = W + (size_t)(k0 + bk) * HDIM + c0 + bd;
      f32x4 r0 = *(const f32x4*)(src);
      f32x4 r1 = *(const f32x4*)(src + HDIM);
      f32x4 r2 = *(const f32x4*)(src + 2 * HDIM);
      f32x4 r3 = *(const f32x4*)(src + 3 * HDIM);
#pragma unroll
      for (int dd = 0; dd < 4; ++dd) {
        bf16x4 p;
        p[0] = (__bf16)r0[dd];
        p[1] = (__bf16)r1[dd];
        p[2] = (__bf16)r2[dd];
        p[3] = (__bf16)r3[dd];
        *(bf16x4*)&Bs[bd + dd][bk] = p;
      }
    }
    __syncthreads();
#pragma unroll
    for (int kk = 0; kk < BK; kk += 32) {
      int ko = kk + quad * 8;
      bf16x8 a0 = *(const bf16x8*)&As[wm + lm][ko];
      bf16x8 a1 = *(const bf16x8*)&As[wm + 16 + lm][ko];
      bf16x8 b0 = *(const bf16x8*)&Bs[wn + lm][ko];
      bf16x8 b1 = *(const bf16x8*)&Bs[wn + 16 + lm][ko];
      acc[0][0] = mfma_bf16(a0, b0, acc[0][0]);
      acc[0][1] = mfma_bf16(a0, b1, acc[0][1]);
      acc[1][0] = mfma_bf16(a1, b0, acc[1][0]);
      acc[1][1] = mfma_bf16(a1, b1, acc[1][1]);
    }
    __syncthreads();
  }

#pragma unroll
  for (int i = 0; i < 2; ++i)
#pragma unroll
    for (int j = 0; j < 2; ++j)
#pragma unroll
      for (int r = 0; r < 4; ++r) {
        int lr = wm + i * 16 + quad * 4 + r;
        int rid = rows_s[lr];
        if (rid >= 0) {
          int gc = c0 + wn + j * 16 + lm;
          float w = wts_s[lr];
          unsafeAtomicAdd(&out[(size_t)(rid >> 1) * HDIM + gc], acc[i][j][r] * w);
        }
      }
}

extern "C" void kernel_launch(void* const* d_in, const int* in_sizes, int n_in,
                              void* d_out, int out_size, void* d_ws, size_t ws_size,
                              hipStream_t stream) {
  const float* x  = (const float*)d_in[0];
  const float* rw = (const float*)d_in[1];
  const float* up = (const float*)d_in[2];
  const float* dw = (const float*)d_in[3];
  float* out = (float*)d_out;

  char* ws = (char*)d_ws;
  int* counts     = (int*)ws;                                  // 32 B
  int* tok_list   = (int*)(ws + 4096);                         // 64 KB
  float* wt_list  = (float*)(ws + 4096 + NEXP * NTOK * 4);     // 64 KB
  __bf16* xb      = (__bf16*)(ws + (1u << 20));                // 4 MB @ 1MB
  __bf16* hidden  = (__bf16*)(ws + (8u << 20));                // 8 MB @ 8MB
  (void)ws_size; (void)n_in; (void)in_sizes;

  hipMemsetAsync(counts, 0, NEXP * sizeof(int), stream);
  hipMemsetAsync(d_out, 0, (size_t)out_size * sizeof(float), stream);
  router_kernel<<<NTOK, 64, 0, stream>>>(x, rw, xb, counts, tok_list, wt_list);
  up_kernel<<<dim3(NTOK / BM, DDIM / BN, NEXP), 256, 0, stream>>>(
      xb, up, counts, tok_list, hidden);
  down_kernel<<<dim3(NTOK / BM, HDIM / BN, NEXP), 256, 0, stream>>>(
      hidden, dw, counts, tok_list, wt_list, out);
}

// Round 2
// 303.439 us; speedup vs baseline: 1.4681x; 1.4681x over previous
//
#include <hip/hip_runtime.h>
#include <hip/hip_bf16.h>

#define NTOK 2048
#define HDIM 1024
#define DDIM 1024
#define NEXP 8

typedef __bf16 bf16x8 __attribute__((ext_vector_type(8)));
typedef float f32x4 __attribute__((ext_vector_type(4)));

__device__ __forceinline__ f32x4 mfma16(bf16x8 a, bf16x8 b, f32x4 c) {
  return __builtin_amdgcn_mfma_f32_16x16x32_bf16(a, b, c, 0, 0, 0);
}

__device__ __forceinline__ void async_copy16(const void* g, void* l) {
  __builtin_amdgcn_global_load_lds(
      (const __attribute__((address_space(1))) void*)g,
      (__attribute__((address_space(3))) void*)l, 16, 0, 0);
}

// ---------------- router: logits -> top2 -> expert lists; also x -> bf16 ----------------
__global__ __launch_bounds__(64) void router_kernel(
    const float* __restrict__ x, const float* __restrict__ rw,
    __bf16* __restrict__ xb, int* __restrict__ counts,
    int* __restrict__ tok_list, float* __restrict__ wt_list)
{
  int n = blockIdx.x;
  int t = threadIdx.x;
  const float* xr = x + (size_t)n * HDIM;
  float acc[NEXP];
#pragma unroll
  for (int e = 0; e < NEXP; ++e) acc[e] = 0.f;
  float xv[16];
#pragma unroll
  for (int i = 0; i < 16; ++i) {
    int h = t + 64 * i;
    float v = xr[h];
    xv[i] = v;
#pragma unroll
    for (int e = 0; e < NEXP; ++e) acc[e] += v * rw[e * HDIM + h];
  }
#pragma unroll
  for (int e = 0; e < NEXP; ++e) {
    float v = acc[e];
#pragma unroll
    for (int off = 32; off > 0; off >>= 1) v += __shfl_xor(v, off, 64);
    acc[e] = v;
  }
#pragma unroll
  for (int i = 0; i < 16; ++i)
    xb[(size_t)n * HDIM + t + 64 * i] = (__bf16)xv[i];

  if (t == 0) {
    int i1 = 0; float l1 = acc[0];
#pragma unroll
    for (int e = 1; e < NEXP; ++e) if (acc[e] > l1) { l1 = acc[e]; i1 = e; }
    int i2 = -1; float l2 = -3.4e38f;
#pragma unroll
    for (int e = 0; e < NEXP; ++e) if (e != i1 && acc[e] > l2) { l2 = acc[e]; i2 = e; }
    float m = fmaxf(l1, l2);
    float p1 = __expf(l1 - m), p2 = __expf(l2 - m);
    float inv = 1.f / (p1 + p2);
    int pos1 = atomicAdd(&counts[i1], 1);
    tok_list[i1 * NTOK + pos1] = n * 2;       // hidden row id = 2n + slot
    wt_list[i1 * NTOK + pos1] = p1 * inv;
    int pos2 = atomicAdd(&counts[i2], 1);
    tok_list[i2 * NTOK + pos2] = n * 2 + 1;
    wt_list[i2 * NTOK + pos2] = p2 * inv;
  }
}

// ---------------- transpose+convert: fp32 [E][1024][NC] -> bf16 [E][NC][1024] ----------------
// REMAP (up_proj): dst col n -> src col ((n>>7)<<6) + (n&63) + ((n>>6)&1)*1024
// so each 128-col dst group = {gate d-block 64, up d-block 64} for the same d range.
template<int NC, bool REMAP>
__global__ __launch_bounds__(256) void convert_kernel(
    const float* __restrict__ src, __bf16* __restrict__ dst)
{
  const int K = 1024;
  int e = blockIdx.z;
  int k0 = blockIdx.x * 64;
  int n0 = blockIdx.y * 64;
  __shared__ __bf16 Lt[64][72];   // [n][k], row stride 144 B (16B-aligned)
  int t = threadIdx.x;
  int src_base = REMAP ? (((n0 >> 7) << 6) + (((n0 >> 6) & 1) << 10)) : n0;
  const float* S = src + ((size_t)e * K + k0) * NC + src_base;
  int kr = t >> 4;
  int c4 = (t & 15) * 4;
#pragma unroll
  for (int rr = 0; rr < 4; ++rr) {
    int k = kr + rr * 16;
    f32x4 v = *(const f32x4*)(S + (size_t)k * NC + c4);
    Lt[c4 + 0][k] = (__bf16)v[0];
    Lt[c4 + 1][k] = (__bf16)v[1];
    Lt[c4 + 2][k] = (__bf16)v[2];
    Lt[c4 + 3][k] = (__bf16)v[3];
  }
  __syncthreads();
  int n = t >> 2;
  int kc = (t & 3) * 16;
  bf16x8 o0 = *(const bf16x8*)&Lt[n][kc];
  bf16x8 o1 = *(const bf16x8*)&Lt[n][kc + 8];
  __bf16* D = dst + ((size_t)e * NC + n0 + n) * K + k0 + kc;
  *(bf16x8*)D = o0;
  *(bf16x8*)(D + 8) = o1;
}

// ---------------- m97-style gathered GEMM: 128x128x64, 4 waves x (32 rows x 128 cols) ----
// A: bf16 [rows][1024] gathered via tok_list. B: bf16 [E][NC][1024] k-contiguous.
// LDS tiles 128x64 bf16, chunk-XOR swizzle; staged with global_load_lds dwordx4.
// IS_UP: cols 0-63 of tile = gate, 64-127 = up (same d range) -> SwiGLU in-lane.
template<bool IS_UP>
__global__ __launch_bounds__(256, 2) void moe_gemm_kernel(
    const __bf16* __restrict__ Atok, const __bf16* __restrict__ Wt,
    const int* __restrict__ counts, const int* __restrict__ tok_list,
    const float* __restrict__ wt_list,
    __bf16* __restrict__ hidden, float* __restrict__ out)
{
  const int NC = IS_UP ? 2048 : 1024;
  int e = blockIdx.z;
  int nrows = counts[e];
  int m0 = blockIdx.x * 128;
  if (m0 >= nrows) return;
  int n0 = blockIdx.y * 128;

  __shared__ __bf16 As[128 * 64];
  __shared__ __bf16 Bs[128 * 64];
  __shared__ int rows_s[128];
  __shared__ float wts_s[128];

  int t = threadIdx.x;
  if (t < 128) {
    int idx = m0 + t;
    rows_s[t] = (idx < nrows) ? tok_list[e * NTOK + idx] : -1;
    wts_s[t] = (idx < nrows && !IS_UP) ? wt_list[e * NTOK + idx] : 0.f;
  }
  __syncthreads();

  int w = t >> 6, lane = t & 63;
  int lm = lane & 15, quad = lane >> 4;

  // staging source pointers: slot s = j*256 + t; row r = s>>3; lds chunk = s&7;
  // global chunk cg = (s&7) ^ (r&7)  (XOR swizzle -> 2-way-max ds_read conflicts, free)
  const __bf16* pA[4];
  const __bf16* pB[4];
#pragma unroll
  for (int j = 0; j < 4; ++j) {
    int s = j * 256 + t;
    int r = s >> 3;
    int cg = (s & 7) ^ (r & 7);
    int rid = rows_s[r];
    int arow = (rid < 0) ? 0 : (IS_UP ? (rid >> 1) : rid);
    pA[j] = Atok + (size_t)arow * 1024 + cg * 8;
    pB[j] = Wt + ((size_t)e * NC + n0 + r) * 1024 + cg * 8;
  }

  f32x4 acc[2][8];
#pragma unroll
  for (int i = 0; i < 2; ++i)
#pragma unroll
    for (int j = 0; j < 8; ++j) acc[i][j] = (f32x4){0.f, 0.f, 0.f, 0.f};

  for (int k0 = 0; k0 < 1024; k0 += 64) {
#pragma unroll
    for (int j = 0; j < 4; ++j) {
      async_copy16(pA[j] + k0, (char*)As + (j * 256 + w * 64) * 16);
      async_copy16(pB[j] + k0, (char*)Bs + (j * 256 + w * 64) * 16);
    }
    __syncthreads();   // drains vmcnt before barrier (compiler-inserted)
#pragma unroll
    for (int kk = 0; kk < 2; ++kk) {
      bf16x8 a[2], b[8];
#pragma unroll
      for (int i = 0; i < 2; ++i) {
        int R = w * 32 + i * 16 + lm;
        int c = (quad + kk * 4) ^ (R & 7);
        a[i] = *(const bf16x8*)((char*)As + (size_t)(R * 8 + c) * 16);
      }
#pragma unroll
      for (int j = 0; j < 8; ++j) {
        int R = j * 16 + lm;
        int c = (quad + kk * 4) ^ (R & 7);
        b[j] = *(const bf16x8*)((char*)Bs + (size_t)(R * 8 + c) * 16);
      }
#pragma unroll
      for (int i = 0; i < 2; ++i)
#pragma unroll
        for (int j = 0; j < 8; ++j)
          acc[i][j] = mfma16(a[i], b[j], acc[i][j]);
    }
    __syncthreads();
  }

  if (IS_UP) {
    int dbase = n0 >> 1;   // 64 unique d per 128-wide tile
#pragma unroll
    for (int i = 0; i < 2; ++i)
#pragma unroll
      for (int j = 0; j < 4; ++j)
#pragma unroll
        for (int r = 0; r < 4; ++r) {
          int lr = w * 32 + i * 16 + quad * 4 + r;   // C/D: row = quad*4+reg
          int rid = rows_s[lr];
          if (rid >= 0) {
            float g = acc[i][j][r];
            float u = acc[i][j + 4][r];
            float hv = g / (1.f + __expf(-g)) * u;
            hidden[(size_t)rid * DDIM + dbase + j * 16 + lm] = (__bf16)hv;
          }
        }
  } else {
#pragma unroll
    for (int i = 0; i < 2; ++i)
#pragma unroll
      for (int j = 0; j < 8; ++j)
#pragma unroll
        for (int r = 0; r < 4; ++r) {
          int lr = w * 32 + i * 16 + quad * 4 + r;
          int rid = rows_s[lr];
          if (rid >= 0) {
            unsafeAtomicAdd(&out[(size_t)(rid >> 1) * HDIM + n0 + j * 16 + lm],
                            acc[i][j][r] * wts_s[lr]);
          }
        }
  }
}

extern "C" void kernel_launch(void* const* d_in, const int* in_sizes, int n_in,
                              void* d_out, int out_size, void* d_ws, size_t ws_size,
                              hipStream_t stream) {
  const float* x  = (const float*)d_in[0];
  const float* rw = (const float*)d_in[1];
  const float* up = (const float*)d_in[2];
  const float* dw = (const float*)d_in[3];
  float* out = (float*)d_out;

  char* ws = (char*)d_ws;
  int* counts    = (int*)ws;                                   // 32 B
  int* tok_list  = (int*)(ws + 4096);                          // 64 KB
  float* wt_list = (float*)(ws + 4096 + NEXP * NTOK * 4);      // 64 KB
  __bf16* xb     = (__bf16*)(ws + (1u << 20));                 // 4 MB  @ 1 MB
  __bf16* hidden = (__bf16*)(ws + (8u << 20));                 // 8 MB  @ 8 MB
  __bf16* wup    = (__bf16*)(ws + (16u << 20));                // 32 MB @ 16 MB
  __bf16* wdn    = (__bf16*)(ws + (48u << 20));                // 16 MB @ 48 MB
  (void)ws_size; (void)n_in; (void)in_sizes;

  hipMemsetAsync(counts, 0, NEXP * sizeof(int), stream);
  hipMemsetAsync(d_out, 0, (size_t)out_size * sizeof(float), stream);

  router_kernel<<<NTOK, 64, 0, stream>>>(x, rw, xb, counts, tok_list, wt_list);
  convert_kernel<2048, true><<<dim3(16, 32, NEXP), 256, 0, stream>>>(up, wup);
  convert_kernel<1024, false><<<dim3(16, 16, NEXP), 256, 0, stream>>>(dw, wdn);
  moe_gemm_kernel<true><<<dim3(16, 16, NEXP), 256, 0, stream>>>(
      xb, wup, counts, tok_list, wt_list, hidden, out);
  moe_gemm_kernel<false><<<dim3(16, 8, NEXP), 256, 0, stream>>>(
      hidden, wdn, counts, tok_list, wt_list, hidden, out);
}

// Round 3
// 260.668 us; speedup vs baseline: 1.7090x; 1.1641x over previous
//
#include <hip/hip_runtime.h>
#include <hip/hip_bf16.h>

#define NTOK 2048
#define HDIM 1024
#define DDIM 1024
#define NEXP 8
#define MAXMB 40

typedef __bf16 bf16x8 __attribute__((ext_vector_type(8)));
typedef float f32x4 __attribute__((ext_vector_type(4)));

__device__ __forceinline__ f32x4 mfma16(bf16x8 a, bf16x8 b, f32x4 c) {
  return __builtin_amdgcn_mfma_f32_16x16x32_bf16(a, b, c, 0, 0, 0);
}

__device__ __forceinline__ void async_copy16(const void* g, void* l) {
  __builtin_amdgcn_global_load_lds(
      (const __attribute__((address_space(1))) void*)g,
      (__attribute__((address_space(3))) void*)l, 16, 0, 0);
}

// -------- transpose+convert 64k x 64n tile: fp32 [E][1024][NC] -> bf16 [E][NC][1024] ----
// k-pairs packed into u32 in LDS [n][34] (conflict-free); 16B-aligned vector IO both sides.
// REMAP (up_proj): dst col n -> src col ((n>>7)<<6)+(n&63)+((n>>6)&1)*1024 so each 128-col
// dst group = {gate d-block, up d-block} for the same d range.
template<int NC, bool REMAP>
__device__ __forceinline__ void conv_body(const float* __restrict__ src,
                                          __bf16* __restrict__ dst,
                                          int e, int k0, int n0,
                                          unsigned int (*Lp)[34])
{
  int t = threadIdx.x;
  int src_col = REMAP ? (((n0 >> 7) << 6) + (((n0 >> 6) & 1) << 10)) : n0;
  const float* S = src + ((size_t)e * 1024 + k0) * NC + src_col;
  int q = t >> 4;          // 0..15
  int c4 = (t & 15) * 4;   // n offset
#pragma unroll
  for (int rep = 0; rep < 2; ++rep) {
    int k = q * 2 + rep * 32;
    f32x4 v0 = *(const f32x4*)(S + (size_t)k * NC + c4);
    f32x4 v1 = *(const f32x4*)(S + (size_t)(k + 1) * NC + c4);
#pragma unroll
    for (int i = 0; i < 4; ++i) {
      union { unsigned int u; __bf16 h[2]; } p;
      p.h[0] = (__bf16)v0[i];
      p.h[1] = (__bf16)v1[i];
      Lp[c4 + i][q + rep * 16] = p.u;   // bank = (n + k/2) % 32 -> 2-way max (free)
    }
  }
  __syncthreads();
  int n = t >> 2, c = t & 3;
  uint2 a0 = *(const uint2*)&Lp[n][4 * c];
  uint2 a1 = *(const uint2*)&Lp[n][4 * c + 2];
  uint2 b0 = *(const uint2*)&Lp[n][16 + 4 * c];
  uint2 b1 = *(const uint2*)&Lp[n][16 + 4 * c + 2];
  char* D = (char*)(dst + ((size_t)e * NC + n0 + n) * 1024 + k0);
  *(uint4*)(D + 16 * c)      = make_uint4(a0.x, a0.y, a1.x, a1.y);
  *(uint4*)(D + 64 + 16 * c) = make_uint4(b0.x, b0.y, b1.x, b1.y);
}

// -------- merged prep: conv_up [0,4096) | conv_dn [4096,6144) | router [6144,6656) -----
__global__ __launch_bounds__(256) void prep_kernel(
    const float* __restrict__ x, const float* __restrict__ rw,
    const float* __restrict__ up, const float* __restrict__ dw,
    __bf16* __restrict__ xb, __bf16* __restrict__ wup, __bf16* __restrict__ wdn,
    int* __restrict__ counts, int* __restrict__ tok_list, float* __restrict__ wt_list)
{
  __shared__ unsigned int Lp[64][34];
  int bid = blockIdx.x;
  if (bid < 4096) {
    int kb = bid & 15, y = (bid >> 4) & 31, e = bid >> 9;
    conv_body<2048, true>(up, wup, e, kb * 64, y * 64, Lp);
    return;
  }
  if (bid < 6144) {
    int b = bid - 4096;
    int kb = b & 15, y = (b >> 4) & 15, e = b >> 8;
    conv_body<1024, false>(dw, wdn, e, kb * 64, y * 64, Lp);
    return;
  }
  // router: 4 tokens per block, one per wave
  int wave = threadIdx.x >> 6, lane = threadIdx.x & 63;
  int n = (bid - 6144) * 4 + wave;
  const float* xr = x + (size_t)n * HDIM;
  float acc[NEXP];
#pragma unroll
  for (int e = 0; e < NEXP; ++e) acc[e] = 0.f;
  float xv[16];
#pragma unroll
  for (int i = 0; i < 16; ++i) {
    int h = lane + 64 * i;
    float v = xr[h];
    xv[i] = v;
#pragma unroll
    for (int e = 0; e < NEXP; ++e) acc[e] += v * rw[e * HDIM + h];
  }
#pragma unroll
  for (int e = 0; e < NEXP; ++e) {
    float v = acc[e];
#pragma unroll
    for (int off = 32; off > 0; off >>= 1) v += __shfl_xor(v, off, 64);
    acc[e] = v;
  }
#pragma unroll
  for (int i = 0; i < 16; ++i)
    xb[(size_t)n * HDIM + lane + 64 * i] = (__bf16)xv[i];

  if (lane == 0) {
    int i1 = 0; float l1 = acc[0];
#pragma unroll
    for (int e = 1; e < NEXP; ++e) if (acc[e] > l1) { l1 = acc[e]; i1 = e; }
    int i2 = -1; float l2 = -3.4e38f;
#pragma unroll
    for (int e = 0; e < NEXP; ++e) if (e != i1 && acc[e] > l2) { l2 = acc[e]; i2 = e; }
    float m = fmaxf(l1, l2);
    float p1 = __expf(l1 - m), p2 = __expf(l2 - m);
    float inv = 1.f / (p1 + p2);
    int pos1 = atomicAdd(&counts[i1], 1);
    tok_list[i1 * NTOK + pos1] = n * 2;      // hidden row id = 2n + slot
    wt_list[i1 * NTOK + pos1] = p1 * inv;
    int pos2 = atomicAdd(&counts[i2], 1);
    tok_list[i2 * NTOK + pos2] = n * 2 + 1;
    wt_list[i2 * NTOK + pos2] = p2 * inv;
  }
}

// -------- scheduler: compact (expert, m0) work list; Σceil(c_e/128) <= 40 --------------
__global__ void sched_kernel(const int* __restrict__ counts,
                             int* __restrict__ mbe, int* __restrict__ mbm0)
{
  if (threadIdx.x == 0) {
    int idx = 0;
    for (int e = 0; e < NEXP; ++e) {
      int c = counts[e];
      for (int m0 = 0; m0 < c; m0 += 128) { mbe[idx] = e; mbm0[idx] = m0; ++idx; }
    }
    for (; idx < MAXMB; ++idx) mbe[idx] = -1;
  }
}

// -------- m97-style gathered GEMM: 128x128x64, compact work list ------------------------
// IS_UP: cols 0-63 = gate, 64-127 = up (same d range) -> SwiGLU in-lane; else down+atomic.
template<bool IS_UP>
__global__ __launch_bounds__(256, 4) void moe_gemm_kernel(
    const __bf16* __restrict__ Atok, const __bf16* __restrict__ Wt,
    const int* __restrict__ mbe, const int* __restrict__ mbm0,
    const int* __restrict__ counts, const int* __restrict__ tok_list,
    const float* __restrict__ wt_list,
    __bf16* __restrict__ hidden, float* __restrict__ out)
{
  const int NC = IS_UP ? 2048 : 1024;
  int mb = blockIdx.x;
  int e = mbe[mb];
  if (e < 0) return;
  int m0 = mbm0[mb];
  int nrows = counts[e];
  int n0 = blockIdx.y * 128;
  int kbeg = IS_UP ? 0 : (blockIdx.z * 512);
  int kend = IS_UP ? 1024 : (kbeg + 512);

  __shared__ __bf16 As[128 * 64];
  __shared__ __bf16 Bs[128 * 64];
  __shared__ int rows_s[128];
  __shared__ float wts_s[128];

  int t = threadIdx.x;
  if (t < 128) {
    int idx = m0 + t;
    rows_s[t] = (idx < nrows) ? tok_list[e * NTOK + idx] : -1;
    wts_s[t] = (idx < nrows && !IS_UP) ? wt_list[e * NTOK + idx] : 0.f;
  }
  __syncthreads();

  int w = t >> 6, lane = t & 63;
  int lm = lane & 15, quad = lane >> 4;

  // staging: slot s = j*256 + t; row r = s>>3; lds chunk = s&7; global chunk = (s&7)^(r&7)
  const __bf16* pA[4];
  const __bf16* pB[4];
#pragma unroll
  for (int j = 0; j < 4; ++j) {
    int s = j * 256 + t;
    int r = s >> 3;
    int cg = (s & 7) ^ (r & 7);
    int rid = rows_s[r];
    int arow = (rid < 0) ? 0 : (IS_UP ? (rid >> 1) : rid);
    pA[j] = Atok + (size_t)arow * 1024 + cg * 8;
    pB[j] = Wt + ((size_t)e * NC + n0 + r) * 1024 + cg * 8;
  }

  f32x4 acc[2][8];
#pragma unroll
  for (int i = 0; i < 2; ++i)
#pragma unroll
    for (int j = 0; j < 8; ++j) acc[i][j] = (f32x4){0.f, 0.f, 0.f, 0.f};

  for (int k0 = kbeg; k0 < kend; k0 += 64) {
#pragma unroll
    for (int j = 0; j < 4; ++j) {
      async_copy16(pA[j] + k0, (char*)As + (j * 256 + w * 64) * 16);
      async_copy16(pB[j] + k0, (char*)Bs + (j * 256 + w * 64) * 16);
    }
    __syncthreads();
#pragma unroll
    for (int kk = 0; kk < 2; ++kk) {
      bf16x8 a[2], b[8];
#pragma unroll
      for (int i = 0; i < 2; ++i) {
        int R = w * 32 + i * 16 + lm;
        int c = (quad + kk * 4) ^ (R & 7);
        a[i] = *(const bf16x8*)((char*)As + (size_t)(R * 8 + c) * 16);
      }
#pragma unroll
      for (int j = 0; j < 8; ++j) {
        int R = j * 16 + lm;
        int c = (quad + kk * 4) ^ (R & 7);
        b[j] = *(const bf16x8*)((char*)Bs + (size_t)(R * 8 + c) * 16);
      }
#pragma unroll
      for (int i = 0; i < 2; ++i)
#pragma unroll
        for (int j = 0; j < 8; ++j)
          acc[i][j] = mfma16(a[i], b[j], acc[i][j]);
    }
    __syncthreads();
  }

  if (IS_UP) {
    int dbase = n0 >> 1;   // 64 unique d per 128-wide tile
#pragma unroll
    for (int i = 0; i < 2; ++i)
#pragma unroll
      for (int j = 0; j < 4; ++j)
#pragma unroll
        for (int r = 0; r < 4; ++r) {
          int lr = w * 32 + i * 16 + quad * 4 + r;   // C/D: row = quad*4+reg
          int rid = rows_s[lr];
          if (rid >= 0) {
            float g = acc[i][j][r];
            float u = acc[i][j + 4][r];
            float hv = g / (1.f + __expf(-g)) * u;
            hidden[(size_t)rid * DDIM + dbase + j * 16 + lm] = (__bf16)hv;
          }
        }
  } else {
#pragma unroll
    for (int i = 0; i < 2; ++i)
#pragma unroll
      for (int j = 0; j < 8; ++j)
#pragma unroll
        for (int r = 0; r < 4; ++r) {
          int lr = w * 32 + i * 16 + quad * 4 + r;
          int rid = rows_s[lr];
          if (rid >= 0) {
            unsafeAtomicAdd(&out[(size_t)(rid >> 1) * HDIM + n0 + j * 16 + lm],
                            acc[i][j][r] * wts_s[lr]);
          }
        }
  }
}

extern "C" void kernel_launch(void* const* d_in, const int* in_sizes, int n_in,
                              void* d_out, int out_size, void* d_ws, size_t ws_size,
                              hipStream_t stream) {
  const float* x  = (const float*)d_in[0];
  const float* rw = (const float*)d_in[1];
  const float* up = (const float*)d_in[2];
  const float* dw = (const float*)d_in[3];
  float* out = (float*)d_out;

  char* ws = (char*)d_ws;
  int* counts    = (int*)ws;                                   // 32 B
  int* mbe       = (int*)(ws + 256);                           // 160 B
  int* mbm0      = (int*)(ws + 512);                           // 160 B
  int* tok_list  = (int*)(ws + 4096);                          // 64 KB
  float* wt_list = (float*)(ws + 4096 + NEXP * NTOK * 4);      // 64 KB
  __bf16* xb     = (__bf16*)(ws + (1u << 20));                 // 4 MB  @ 1 MB
  __bf16* hidden = (__bf16*)(ws + (8u << 20));                 // 8 MB  @ 8 MB
  __bf16* wup    = (__bf16*)(ws + (16u << 20));                // 32 MB @ 16 MB
  __bf16* wdn    = (__bf16*)(ws + (48u << 20));                // 16 MB @ 48 MB
  (void)ws_size; (void)n_in; (void)in_sizes;

  hipMemsetAsync(counts, 0, NEXP * sizeof(int), stream);
  hipMemsetAsync(d_out, 0, (size_t)out_size * sizeof(float), stream);

  prep_kernel<<<6656, 256, 0, stream>>>(x, rw, up, dw, xb, wup, wdn,
                                        counts, tok_list, wt_list);
  sched_kernel<<<1, 64, 0, stream>>>(counts, mbe, mbm0);
  moe_gemm_kernel<true><<<dim3(MAXMB, 16, 1), 256, 0, stream>>>(
      xb, wup, mbe, mbm0, counts, tok_list, wt_list, hidden, out);
  moe_gemm_kernel<false><<<dim3(MAXMB, 8, 2), 256, 0, stream>>>(
      hidden, wdn, mbe, mbm0, counts, tok_list, wt_list, hidden, out);
}

// Round 4
// 251.562 us; speedup vs baseline: 1.7709x; 1.0362x over previous
//
#include <hip/hip_runtime.h>
#include <hip/hip_bf16.h>

#define NTOK 2048
#define HDIM 1024
#define DDIM 1024
#define NEXP 8
#define MAXMB 40

typedef __bf16 bf16x8 __attribute__((ext_vector_type(8)));
typedef float f32x4 __attribute__((ext_vector_type(4)));

__device__ __forceinline__ f32x4 mfma16(bf16x8 a, bf16x8 b, f32x4 c) {
  return __builtin_amdgcn_mfma_f32_16x16x32_bf16(a, b, c, 0, 0, 0);
}

__device__ __forceinline__ void async_copy16(const void* g, void* l) {
  __builtin_amdgcn_global_load_lds(
      (const __attribute__((address_space(1))) void*)g,
      (__attribute__((address_space(3))) void*)l, 16, 0, 0);
}

// -------- 4-tile pipelined transpose+convert: 256k x 64n, fp32 [E][1024][NC] -> bf16
// [E][NC][1024]. All 16 f32x4 loads issued before first use (one latency / 4 tiles).
// REMAP (up_proj): dst col n -> src col ((n>>7)<<6)+(n&63)+((n>>6)&1)*1024 so each
// 128-col dst group = {gate d-block, up d-block} for the same d range.
template<int NC, bool REMAP>
__device__ __forceinline__ void conv4(const float* __restrict__ src,
                                      __bf16* __restrict__ dst,
                                      int e, int k0, int n0,
                                      unsigned int (*Lp)[34])
{
  int t = threadIdx.x;
  int src_col = REMAP ? (((n0 >> 7) << 6) + (((n0 >> 6) & 1) << 10)) : n0;
  const float* S = src + ((size_t)e * 1024 + k0) * NC + src_col;
  int q = t >> 4;          // 0..15
  int c4 = (t & 15) * 4;   // n offset
  f32x4 v[16];
#pragma unroll
  for (int tile = 0; tile < 4; ++tile)
#pragma unroll
    for (int rep = 0; rep < 2; ++rep) {
      int k = tile * 64 + q * 2 + rep * 32;
      v[tile * 4 + rep * 2]     = *(const f32x4*)(S + (size_t)k * NC + c4);
      v[tile * 4 + rep * 2 + 1] = *(const f32x4*)(S + (size_t)(k + 1) * NC + c4);
    }
#pragma unroll
  for (int tile = 0; tile < 4; ++tile) {
    if (tile) __syncthreads();
#pragma unroll
    for (int rep = 0; rep < 2; ++rep)
#pragma unroll
      for (int i = 0; i < 4; ++i) {
        union { unsigned int u; __bf16 h[2]; } p;
        p.h[0] = (__bf16)v[tile * 4 + rep * 2][i];
        p.h[1] = (__bf16)v[tile * 4 + rep * 2 + 1][i];
        Lp[c4 + i][q + rep * 16] = p.u;   // k-pairs packed in u32
      }
    __syncthreads();
    int n = t >> 2, c = t & 3;
    uint2 a0 = *(const uint2*)&Lp[n][4 * c];
    uint2 a1 = *(const uint2*)&Lp[n][4 * c + 2];
    uint2 b0 = *(const uint2*)&Lp[n][16 + 4 * c];
    uint2 b1 = *(const uint2*)&Lp[n][16 + 4 * c + 2];
    char* D = (char*)(dst + ((size_t)e * NC + n0 + n) * 1024 + k0 + tile * 64);
    *(uint4*)(D + 16 * c)      = make_uint4(a0.x, a0.y, a1.x, a1.y);
    *(uint4*)(D + 64 + 16 * c) = make_uint4(b0.x, b0.y, b1.x, b1.y);
  }
}

// -------- prep: router [0,512) | conv_up 4-tile [512, 512+1024) ------------------------
__global__ __launch_bounds__(256, 4) void prep_kernel(
    const float* __restrict__ x, const float* __restrict__ rw,
    const float* __restrict__ up,
    __bf16* __restrict__ xb, __bf16* __restrict__ wup,
    int* __restrict__ counts, int* __restrict__ tok_list, float* __restrict__ wt_list)
{
  __shared__ unsigned int Lp[64][34];
  int bid = blockIdx.x;
  if (bid >= 512) {
    int b = bid - 512;                       // 4 kb x 32 y x 8 e = 1024
    int kb = b & 3, y = (b >> 2) & 31, e = b >> 7;
    conv4<2048, true>(up, wup, e, kb * 256, y * 64, Lp);
    return;
  }
  // router: 4 tokens per block, one per wave
  int wave = threadIdx.x >> 6, lane = threadIdx.x & 63;
  int n = bid * 4 + wave;
  const float* xr = x + (size_t)n * HDIM;
  float acc[NEXP];
#pragma unroll
  for (int e = 0; e < NEXP; ++e) acc[e] = 0.f;
  float xv[16];
#pragma unroll
  for (int i = 0; i < 16; ++i) {
    int h = lane + 64 * i;
    float v = xr[h];
    xv[i] = v;
#pragma unroll
    for (int e = 0; e < NEXP; ++e) acc[e] += v * rw[e * HDIM + h];
  }
#pragma unroll
  for (int e = 0; e < NEXP; ++e) {
    float v = acc[e];
#pragma unroll
    for (int off = 32; off > 0; off >>= 1) v += __shfl_xor(v, off, 64);
    acc[e] = v;
  }
#pragma unroll
  for (int i = 0; i < 16; ++i)
    xb[(size_t)n * HDIM + lane + 64 * i] = (__bf16)xv[i];

  if (lane == 0) {
    int i1 = 0; float l1 = acc[0];
#pragma unroll
    for (int e = 1; e < NEXP; ++e) if (acc[e] > l1) { l1 = acc[e]; i1 = e; }
    int i2 = -1; float l2 = -3.4e38f;
#pragma unroll
    for (int e = 0; e < NEXP; ++e) if (e != i1 && acc[e] > l2) { l2 = acc[e]; i2 = e; }
    float m = fmaxf(l1, l2);
    float p1 = __expf(l1 - m), p2 = __expf(l2 - m);
    float inv = 1.f / (p1 + p2);
    int pos1 = atomicAdd(&counts[i1], 1);
    tok_list[i1 * NTOK + pos1] = n * 2;      // hidden row id = 2n + slot
    wt_list[i1 * NTOK + pos1] = p1 * inv;
    int pos2 = atomicAdd(&counts[i2], 1);
    tok_list[i2 * NTOK + pos2] = n * 2 + 1;
    wt_list[i2 * NTOK + pos2] = p2 * inv;
  }
}

// -------- m97-style gathered GEMM body: 128x128x64, inline (e,m0) scheduler -------------
// IS_UP: cols 0-63 = gate, 64-127 = up (same d range) -> SwiGLU in-lane; else down+atomic.
template<bool IS_UP>
__device__ __forceinline__ void gemm_body(
    const __bf16* __restrict__ Atok, const __bf16* __restrict__ Wt,
    const int* __restrict__ counts, const int* __restrict__ tok_list,
    const float* __restrict__ wt_list,
    __bf16* __restrict__ hidden, float* __restrict__ out,
    int mb, int n0, int kbeg, int kend,
    __bf16* As, __bf16* Bs, int* rows_s, float* wts_s)
{
  const int NC = IS_UP ? 2048 : 1024;
  // inline scheduler: mb -> (e, m0)
  int e = -1, m0 = 0, base = 0;
#pragma unroll
  for (int i = 0; i < NEXP; ++i) {
    int c = counts[i];
    int nt = (c + 127) >> 7;
    if (e < 0 && mb < base + nt) { e = i; m0 = (mb - base) << 7; }
    base += nt;
  }
  if (e < 0) return;
  int nrows = counts[e];

  int t = threadIdx.x;
  if (t < 128) {
    int idx = m0 + t;
    rows_s[t] = (idx < nrows) ? tok_list[e * NTOK + idx] : -1;
    wts_s[t] = (idx < nrows && !IS_UP) ? wt_list[e * NTOK + idx] : 0.f;
  }
  __syncthreads();

  int w = t >> 6, lane = t & 63;
  int lm = lane & 15, quad = lane >> 4;

  // staging: slot s = j*256 + t; row r = s>>3; lds chunk = s&7; global chunk = (s&7)^(r&7)
  const __bf16* pA[4];
  const __bf16* pB[4];
#pragma unroll
  for (int j = 0; j < 4; ++j) {
    int s = j * 256 + t;
    int r = s >> 3;
    int cg = (s & 7) ^ (r & 7);
    int rid = rows_s[r];
    int arow = (rid < 0) ? 0 : (IS_UP ? (rid >> 1) : rid);
    pA[j] = Atok + (size_t)arow * 1024 + cg * 8;
    pB[j] = Wt + ((size_t)e * NC + n0 + r) * 1024 + cg * 8;
  }

  f32x4 acc[2][8];
#pragma unroll
  for (int i = 0; i < 2; ++i)
#pragma unroll
    for (int j = 0; j < 8; ++j) acc[i][j] = (f32x4){0.f, 0.f, 0.f, 0.f};

  for (int k0 = kbeg; k0 < kend; k0 += 64) {
#pragma unroll
    for (int j = 0; j < 4; ++j) {
      async_copy16(pA[j] + k0, (char*)As + (j * 256 + w * 64) * 16);
      async_copy16(pB[j] + k0, (char*)Bs + (j * 256 + w * 64) * 16);
    }
    __syncthreads();
#pragma unroll
    for (int kk = 0; kk < 2; ++kk) {
      bf16x8 a[2], b[8];
#pragma unroll
      for (int i = 0; i < 2; ++i) {
        int R = w * 32 + i * 16 + lm;
        int c = (quad + kk * 4) ^ (R & 7);
        a[i] = *(const bf16x8*)((char*)As + (size_t)(R * 8 + c) * 16);
      }
#pragma unroll
      for (int j = 0; j < 8; ++j) {
        int R = j * 16 + lm;
        int c = (quad + kk * 4) ^ (R & 7);
        b[j] = *(const bf16x8*)((char*)Bs + (size_t)(R * 8 + c) * 16);
      }
#pragma unroll
      for (int i = 0; i < 2; ++i)
#pragma unroll
        for (int j = 0; j < 8; ++j)
          acc[i][j] = mfma16(a[i], b[j], acc[i][j]);
    }
    __syncthreads();
  }

  if (IS_UP) {
    int dbase = n0 >> 1;   // 64 unique d per 128-wide tile
#pragma unroll
    for (int i = 0; i < 2; ++i)
#pragma unroll
      for (int j = 0; j < 4; ++j)
#pragma unroll
        for (int r = 0; r < 4; ++r) {
          int lr = w * 32 + i * 16 + quad * 4 + r;   // C/D: row = quad*4+reg
          int rid = rows_s[lr];
          if (rid >= 0) {
            float g = acc[i][j][r];
            float u = acc[i][j + 4][r];
            float hv = g / (1.f + __expf(-g)) * u;
            hidden[(size_t)rid * DDIM + dbase + j * 16 + lm] = (__bf16)hv;
          }
        }
  } else {
#pragma unroll
    for (int i = 0; i < 2; ++i)
#pragma unroll
      for (int j = 0; j < 8; ++j)
#pragma unroll
        for (int r = 0; r < 4; ++r) {
          int lr = w * 32 + i * 16 + quad * 4 + r;
          int rid = rows_s[lr];
          if (rid >= 0) {
            unsafeAtomicAdd(&out[(size_t)(rid >> 1) * HDIM + n0 + j * 16 + lm],
                            acc[i][j][r] * wts_s[lr]);
          }
        }
  }
}

// -------- mid: up-GEMM [0,640) (ny = b&15 -> XCD = ny%8) | conv_dn 4-tile [640,1152) ---
__global__ __launch_bounds__(256, 4) void mid_kernel(
    const __bf16* __restrict__ xb, const __bf16* __restrict__ wup,
    const float* __restrict__ dw, __bf16* __restrict__ wdn,
    const int* __restrict__ counts, const int* __restrict__ tok_list,
    const float* __restrict__ wt_list, __bf16* __restrict__ hidden)
{
  __shared__ __align__(16) char smem[33792];
  int b = blockIdx.x;
  if (b < 640) {
    __bf16* As = (__bf16*)smem;
    __bf16* Bs = (__bf16*)(smem + 16384);
    int* rows_s = (int*)(smem + 32768);
    float* wts_s = (float*)(smem + 33280);
    gemm_body<true>(xb, wup, counts, tok_list, wt_list, hidden, (float*)nullptr,
                    b >> 4, (b & 15) * 128, 0, 1024, As, Bs, rows_s, wts_s);
  } else {
    int tb = b - 640;                        // 4 kb x 16 y x 8 e = 512
    int kb = tb & 3, y = (tb >> 2) & 15, e = tb >> 6;
    conv4<1024, false>(dw, wdn, e, kb * 256, y * 64, (unsigned int (*)[34])smem);
  }
}

// -------- down: grid (8 ny, 40 mb, 2 kz) -> XCD = ny (B-tile L2 locality) --------------
__global__ __launch_bounds__(256, 4) void down_kernel(
    const __bf16* __restrict__ hidden, const __bf16* __restrict__ wdn,
    const int* __restrict__ counts, const int* __restrict__ tok_list,
    const float* __restrict__ wt_list, float* __restrict__ out)
{
  __shared__ __align__(16) char smem[33792];
  __bf16* As = (__bf16*)smem;
  __bf16* Bs = (__bf16*)(smem + 16384);
  int* rows_s = (int*)(smem + 32768);
  float* wts_s = (float*)(smem + 33280);
  int kz = blockIdx.z;
  gemm_body<false>(hidden, wdn, counts, tok_list, wt_list, (__bf16*)nullptr, out,
                   blockIdx.y, blockIdx.x * 128, kz * 512, kz * 512 + 512,
                   As, Bs, rows_s, wts_s);
}

extern "C" void kernel_launch(void* const* d_in, const int* in_sizes, int n_in,
                              void* d_out, int out_size, void* d_ws, size_t ws_size,
                              hipStream_t stream) {
  const float* x  = (const float*)d_in[0];
  const float* rw = (const float*)d_in[1];
  const float* up = (const float*)d_in[2];
  const float* dw = (const float*)d_in[3];
  float* out = (float*)d_out;

  char* ws = (char*)d_ws;
  int* counts    = (int*)ws;                                   // 32 B
  int* tok_list  = (int*)(ws + 4096);                          // 64 KB
  float* wt_list = (float*)(ws + 4096 + NEXP * NTOK * 4);      // 64 KB
  __bf16* xb     = (__bf16*)(ws + (1u << 20));                 // 4 MB  @ 1 MB
  __bf16* hidden = (__bf16*)(ws + (8u << 20));                 // 8 MB  @ 8 MB
  __bf16* wup    = (__bf16*)(ws + (16u << 20));                // 32 MB @ 16 MB
  __bf16* wdn    = (__bf16*)(ws + (48u << 20));                // 16 MB @ 48 MB
  (void)ws_size; (void)n_in; (void)in_sizes;

  hipMemsetAsync(counts, 0, NEXP * sizeof(int), stream);
  hipMemsetAsync(d_out, 0, (size_t)out_size * sizeof(float), stream);

  prep_kernel<<<1536, 256, 0, stream>>>(x, rw, up, xb, wup,
                                        counts, tok_list, wt_list);
  mid_kernel<<<1152, 256, 0, stream>>>(xb, wup, dw, wdn,
                                       counts, tok_list, wt_list, hidden);
  down_kernel<<<dim3(8, MAXMB, 2), 256, 0, stream>>>(
      hidden, wdn, counts, tok_list, wt_list, out);
}

// Round 5
// 247.597 us; speedup vs baseline: 1.7992x; 1.0160x over previous
//
#include <hip/hip_runtime.h>
#include <hip/hip_bf16.h>

#define NTOK 2048
#define HDIM 1024
#define DDIM 1024
#define NEXP 8
#define MAXMB 40

typedef __bf16 bf16x8 __attribute__((ext_vector_type(8)));
typedef float f32x4 __attribute__((ext_vector_type(4)));

__device__ __forceinline__ f32x4 mfma16(bf16x8 a, bf16x8 b, f32x4 c) {
  return __builtin_amdgcn_mfma_f32_16x16x32_bf16(a, b, c, 0, 0, 0);
}

__device__ __forceinline__ void async_copy16(const void* g, void* l) {
  __builtin_amdgcn_global_load_lds(
      (const __attribute__((address_space(1))) void*)g,
      (__attribute__((address_space(3))) void*)l, 16, 0, 0);
}

// -------- depth-2 pipelined transpose+convert: 256k x 64n per block ---------------------
// fp32 [E][1024][NC] -> bf16 [E][NC][1024]. Only 8 f32x4 live (cur/nxt) so no spill;
// next tile's loads are issued before consuming current (vmcnt waits oldest-first, so
// the prefetch stays in flight across the wait).
// REMAP (up_proj): dst col n -> src col ((n>>7)<<6)+(n&63)+((n>>6)&1)*1024 so each
// 128-col dst group = {gate d-block, up d-block} for the same d range.
template<int NC, bool REMAP>
__device__ __forceinline__ void conv4(const float* __restrict__ src,
                                      __bf16* __restrict__ dst,
                                      int e, int k0, int n0,
                                      unsigned int (*Lp)[34])
{
  int t = threadIdx.x;
  int src_col = REMAP ? (((n0 >> 7) << 6) + (((n0 >> 6) & 1) << 10)) : n0;
  const float* S = src + ((size_t)e * 1024 + k0) * NC + src_col;
  int q = t >> 4;          // 0..15
  int c4 = (t & 15) * 4;   // n offset

  f32x4 cur[4], nxt[4];
#pragma unroll
  for (int rep = 0; rep < 2; ++rep) {
    int k = q * 2 + rep * 32;
    cur[rep * 2]     = *(const f32x4*)(S + (size_t)k * NC + c4);
    cur[rep * 2 + 1] = *(const f32x4*)(S + (size_t)(k + 1) * NC + c4);
  }
#pragma unroll
  for (int tile = 0; tile < 4; ++tile) {
    if (tile < 3) {
#pragma unroll
      for (int rep = 0; rep < 2; ++rep) {
        int k = (tile + 1) * 64 + q * 2 + rep * 32;
        nxt[rep * 2]     = *(const f32x4*)(S + (size_t)k * NC + c4);
        nxt[rep * 2 + 1] = *(const f32x4*)(S + (size_t)(k + 1) * NC + c4);
      }
    }
    if (tile) __syncthreads();
#pragma unroll
    for (int rep = 0; rep < 2; ++rep)
#pragma unroll
      for (int i = 0; i < 4; ++i) {
        union { unsigned int u; __bf16 h[2]; } p;
        p.h[0] = (__bf16)cur[rep * 2][i];
        p.h[1] = (__bf16)cur[rep * 2 + 1][i];
        Lp[c4 + i][q + rep * 16] = p.u;   // k-pairs packed in u32; 2-way max (free)
      }
    __syncthreads();
    {
      int n = t >> 2, c = t & 3;
      uint2 a0 = *(const uint2*)&Lp[n][4 * c];
      uint2 a1 = *(const uint2*)&Lp[n][4 * c + 2];
      uint2 b0 = *(const uint2*)&Lp[n][16 + 4 * c];
      uint2 b1 = *(const uint2*)&Lp[n][16 + 4 * c + 2];
      char* D = (char*)(dst + ((size_t)e * NC + n0 + n) * 1024 + k0 + tile * 64);
      *(uint4*)(D + 16 * c)      = make_uint4(a0.x, a0.y, a1.x, a1.y);
      *(uint4*)(D + 64 + 16 * c) = make_uint4(b0.x, b0.y, b1.x, b1.y);
    }
#pragma unroll
    for (int i = 0; i < 4; ++i) cur[i] = nxt[i];
  }
}

// -------- prep: router [0,512) | conv_up 4-tile [512, 512+1024) ------------------------
__global__ __launch_bounds__(256) void prep_kernel(
    const float* __restrict__ x, const float* __restrict__ rw,
    const float* __restrict__ up,
    __bf16* __restrict__ xb, __bf16* __restrict__ wup,
    int* __restrict__ counts, int* __restrict__ tok_list, float* __restrict__ wt_list)
{
  __shared__ unsigned int Lp[64][34];
  int bid = blockIdx.x;
  if (bid >= 512) {
    int b = bid - 512;                       // 4 kb x 32 y x 8 e = 1024
    int kb = b & 3, y = (b >> 2) & 31, e = b >> 7;
    conv4<2048, true>(up, wup, e, kb * 256, y * 64, Lp);
    return;
  }
  // router: 4 tokens per block, one per wave
  int wave = threadIdx.x >> 6, lane = threadIdx.x & 63;
  int n = bid * 4 + wave;
  const float* xr = x + (size_t)n * HDIM;
  float acc[NEXP];
#pragma unroll
  for (int e = 0; e < NEXP; ++e) acc[e] = 0.f;
  float xv[16];
#pragma unroll
  for (int i = 0; i < 16; ++i) {
    int h = lane + 64 * i;
    float v = xr[h];
    xv[i] = v;
#pragma unroll
    for (int e = 0; e < NEXP; ++e) acc[e] += v * rw[e * HDIM + h];
  }
#pragma unroll
  for (int e = 0; e < NEXP; ++e) {
    float v = acc[e];
#pragma unroll
    for (int off = 32; off > 0; off >>= 1) v += __shfl_xor(v, off, 64);
    acc[e] = v;
  }
#pragma unroll
  for (int i = 0; i < 16; ++i)
    xb[(size_t)n * HDIM + lane + 64 * i] = (__bf16)xv[i];

  if (lane == 0) {
    int i1 = 0; float l1 = acc[0];
#pragma unroll
    for (int e = 1; e < NEXP; ++e) if (acc[e] > l1) { l1 = acc[e]; i1 = e; }
    int i2 = -1; float l2 = -3.4e38f;
#pragma unroll
    for (int e = 0; e < NEXP; ++e) if (e != i1 && acc[e] > l2) { l2 = acc[e]; i2 = e; }
    float m = fmaxf(l1, l2);
    float p1 = __expf(l1 - m), p2 = __expf(l2 - m);
    float inv = 1.f / (p1 + p2);
    int pos1 = atomicAdd(&counts[i1], 1);
    tok_list[i1 * NTOK + pos1] = n * 2;      // hidden row id = 2n + slot
    wt_list[i1 * NTOK + pos1] = p1 * inv;
    int pos2 = atomicAdd(&counts[i2], 1);
    tok_list[i2 * NTOK + pos2] = n * 2 + 1;
    wt_list[i2 * NTOK + pos2] = p2 * inv;
  }
}

// -------- m97-style gathered GEMM body: 128x128x64, inline (e,m0) scheduler -------------
// IS_UP: cols 0-63 = gate, 64-127 = up (same d range) -> SwiGLU in-lane; else down+atomic.
template<bool IS_UP>
__device__ __forceinline__ void gemm_body(
    const __bf16* __restrict__ Atok, const __bf16* __restrict__ Wt,
    const int* __restrict__ counts, const int* __restrict__ tok_list,
    const float* __restrict__ wt_list,
    __bf16* __restrict__ hidden, float* __restrict__ out,
    int mb, int n0, int kbeg, int kend,
    __bf16* As, __bf16* Bs, int* rows_s, float* wts_s)
{
  const int NC = IS_UP ? 2048 : 1024;
  // inline scheduler: mb -> (e, m0)
  int e = -1, m0 = 0, base = 0;
#pragma unroll
  for (int i = 0; i < NEXP; ++i) {
    int c = counts[i];
    int nt = (c + 127) >> 7;
    if (e < 0 && mb < base + nt) { e = i; m0 = (mb - base) << 7; }
    base += nt;
  }
  if (e < 0) return;
  int nrows = counts[e];

  int t = threadIdx.x;
  if (t < 128) {
    int idx = m0 + t;
    rows_s[t] = (idx < nrows) ? tok_list[e * NTOK + idx] : -1;
    wts_s[t] = (idx < nrows && !IS_UP) ? wt_list[e * NTOK + idx] : 0.f;
  }
  __syncthreads();

  int w = t >> 6, lane = t & 63;
  int lm = lane & 15, quad = lane >> 4;

  // staging: slot s = j*256 + t; row r = s>>3; lds chunk = s&7; global chunk = (s&7)^(r&7)
  const __bf16* pA[4];
  const __bf16* pB[4];
#pragma unroll
  for (int j = 0; j < 4; ++j) {
    int s = j * 256 + t;
    int r = s >> 3;
    int cg = (s & 7) ^ (r & 7);
    int rid = rows_s[r];
    int arow = (rid < 0) ? 0 : (IS_UP ? (rid >> 1) : rid);
    pA[j] = Atok + (size_t)arow * 1024 + cg * 8;
    pB[j] = Wt + ((size_t)e * NC + n0 + r) * 1024 + cg * 8;
  }

  f32x4 acc[2][8];
#pragma unroll
  for (int i = 0; i < 2; ++i)
#pragma unroll
    for (int j = 0; j < 8; ++j) acc[i][j] = (f32x4){0.f, 0.f, 0.f, 0.f};

  for (int k0 = kbeg; k0 < kend; k0 += 64) {
#pragma unroll
    for (int j = 0; j < 4; ++j) {
      async_copy16(pA[j] + k0, (char*)As + (j * 256 + w * 64) * 16);
      async_copy16(pB[j] + k0, (char*)Bs + (j * 256 + w * 64) * 16);
    }
    __syncthreads();
#pragma unroll
    for (int kk = 0; kk < 2; ++kk) {
      bf16x8 a[2], b[8];
#pragma unroll
      for (int i = 0; i < 2; ++i) {
        int R = w * 32 + i * 16 + lm;
        int c = (quad + kk * 4) ^ (R & 7);
        a[i] = *(const bf16x8*)((char*)As + (size_t)(R * 8 + c) * 16);
      }
#pragma unroll
      for (int j = 0; j < 8; ++j) {
        int R = j * 16 + lm;
        int c = (quad + kk * 4) ^ (R & 7);
        b[j] = *(const bf16x8*)((char*)Bs + (size_t)(R * 8 + c) * 16);
      }
#pragma unroll
      for (int i = 0; i < 2; ++i)
#pragma unroll
        for (int j = 0; j < 8; ++j)
          acc[i][j] = mfma16(a[i], b[j], acc[i][j]);
    }
    __syncthreads();
  }

  if (IS_UP) {
    int dbase = n0 >> 1;   // 64 unique d per 128-wide tile
#pragma unroll
    for (int i = 0; i < 2; ++i)
#pragma unroll
      for (int j = 0; j < 4; ++j)
#pragma unroll
        for (int r = 0; r < 4; ++r) {
          int lr = w * 32 + i * 16 + quad * 4 + r;   // C/D: row = quad*4+reg
          int rid = rows_s[lr];
          if (rid >= 0) {
            float g = acc[i][j][r];
            float u = acc[i][j + 4][r];
            float hv = g / (1.f + __expf(-g)) * u;
            hidden[(size_t)rid * DDIM + dbase + j * 16 + lm] = (__bf16)hv;
          }
        }
  } else {
#pragma unroll
    for (int i = 0; i < 2; ++i)
#pragma unroll
      for (int j = 0; j < 8; ++j)
#pragma unroll
        for (int r = 0; r < 4; ++r) {
          int lr = w * 32 + i * 16 + quad * 4 + r;
          int rid = rows_s[lr];
          if (rid >= 0) {
            unsafeAtomicAdd(&out[(size_t)(rid >> 1) * HDIM + n0 + j * 16 + lm],
                            acc[i][j][r] * wts_s[lr]);
          }
        }
  }
}

// -------- mid: up-GEMM [0,640) (ny = b&15 -> XCD = ny%8) | conv_dn 4-tile [640,1152) ---
__global__ __launch_bounds__(256, 3) void mid_kernel(
    const __bf16* __restrict__ xb, const __bf16* __restrict__ wup,
    const float* __restrict__ dw, __bf16* __restrict__ wdn,
    const int* __restrict__ counts, const int* __restrict__ tok_list,
    const float* __restrict__ wt_list, __bf16* __restrict__ hidden)
{
  __shared__ __align__(16) char smem[33792];
  int b = blockIdx.x;
  if (b < 640) {
    __bf16* As = (__bf16*)smem;
    __bf16* Bs = (__bf16*)(smem + 16384);
    int* rows_s = (int*)(smem + 32768);
    float* wts_s = (float*)(smem + 33280);
    gemm_body<true>(xb, wup, counts, tok_list, wt_list, hidden, (float*)nullptr,
                    b >> 4, (b & 15) * 128, 0, 1024, As, Bs, rows_s, wts_s);
  } else {
    int tb = b - 640;                        // 4 kb x 16 y x 8 e = 512
    int kb = tb & 3, y = (tb >> 2) & 15, e = tb >> 6;
    conv4<1024, false>(dw, wdn, e, kb * 256, y * 64, (unsigned int (*)[34])smem);
  }
}

// -------- down: grid (8 ny, 40 mb, 2 kz) -> XCD = ny (B-tile L2 locality) --------------
__global__ __launch_bounds__(256, 3) void down_kernel(
    const __bf16* __restrict__ hidden, const __bf16* __restrict__ wdn,
    const int* __restrict__ counts, const int* __restrict__ tok_list,
    const float* __restrict__ wt_list, float* __restrict__ out)
{
  __shared__ __align__(16) char smem[33792];
  __bf16* As = (__bf16*)smem;
  __bf16* Bs = (__bf16*)(smem + 16384);
  int* rows_s = (int*)(smem + 32768);
  float* wts_s = (float*)(smem + 33280);
  int kz = blockIdx.z;
  gemm_body<false>(hidden, wdn, counts, tok_list, wt_list, (__bf16*)nullptr, out,
                   blockIdx.y, blockIdx.x * 128, kz * 512, kz * 512 + 512,
                   As, Bs, rows_s, wts_s);
}

extern "C" void kernel_launch(void* const* d_in, const int* in_sizes, int n_in,
                              void* d_out, int out_size, void* d_ws, size_t ws_size,
                              hipStream_t stream) {
  const float* x  = (const float*)d_in[0];
  const float* rw = (const float*)d_in[1];
  const float* up = (const float*)d_in[2];
  const float* dw = (const float*)d_in[3];
  float* out = (float*)d_out;

  char* ws = (char*)d_ws;
  int* counts    = (int*)ws;                                   // 32 B
  int* tok_list  = (int*)(ws + 4096);                          // 64 KB
  float* wt_list = (float*)(ws + 4096 + NEXP * NTOK * 4);      // 64 KB
  __bf16* xb     = (__bf16*)(ws + (1u << 20));                 // 4 MB  @ 1 MB
  __bf16* hidden = (__bf16*)(ws + (8u << 20));                 // 8 MB  @ 8 MB
  __bf16* wup    = (__bf16*)(ws + (16u << 20));                // 32 MB @ 16 MB
  __bf16* wdn    = (__bf16*)(ws + (48u << 20));                // 16 MB @ 48 MB
  (void)ws_size; (void)n_in; (void)in_sizes;

  hipMemsetAsync(counts, 0, NEXP * sizeof(int), stream);
  hipMemsetAsync(d_out, 0, (size_t)out_size * sizeof(float), stream);

  prep_kernel<<<1536, 256, 0, stream>>>(x, rw, up, xb, wup,
                                        counts, tok_list, wt_list);
  mid_kernel<<<1152, 256, 0, stream>>>(xb, wup, dw, wdn,
                                       counts, tok_list, wt_list, hidden);
  down_kernel<<<dim3(8, MAXMB, 2), 256, 0, stream>>>(
      hidden, wdn, counts, tok_list, wt_list, out);
}